// Round 2
// baseline (52.416 us; speedup 1.0000x reference)
//
#include <hip/hip_runtime.h>

// Causal depthwise Conv1d: x[B,L,C] (f32), weight[C,1,K] (f32), bias[C] (f32)
// y[b,l,c] = bias[c] + sum_{k=0..K-1} w[c,0,k] * x[b, l-(K-1)+k, c], zero-pad left.
// B=8, L=4096, C=1024, K=7. Memory-bound streaming kernel.
// LT=16: 256x8=2048 blocks -> 8 blocks/CU (256 thr = 4 waves each) = 32 waves/CU (max occupancy).

constexpr int Lc  = 4096;
constexpr int C4  = 256;   // C / 4 float4 lanes
constexpr int K   = 7;
constexpr int LT  = 16;    // L positions per block (rolling window in registers)

__global__ __launch_bounds__(256) void dwconv_kernel(
    const float4* __restrict__ x, const float* __restrict__ w,
    const float* __restrict__ bias, float4* __restrict__ y) {
  const int c4 = threadIdx.x;          // 0..255  -> channels c4*4 .. c4*4+3
  const int l0 = blockIdx.x * LT;      // L-tile start
  const int b  = blockIdx.y;           // batch
  const int c  = c4 * 4;

  // Per-thread weights for its 4 channels: w[c+j][k]
  float wk[K][4];
#pragma unroll
  for (int k = 0; k < K; ++k) {
#pragma unroll
    for (int j = 0; j < 4; ++j) {
      wk[k][j] = w[(c + j) * K + k];
    }
  }

  float4 bv;
  bv.x = bias[c + 0];
  bv.y = bias[c + 1];
  bv.z = bias[c + 2];
  bv.w = bias[c + 3];

  const float4* xb = x + (size_t)b * Lc * C4 + c4;
  float4*       yb = y + (size_t)b * Lc * C4 + c4;

  // Rolling window: before iteration i, slots (i+0)%K .. (i+K-2)%K hold
  // x[l0+i-6 .. l0+i-1]; we load x[l0+i] into slot (i+K-1)%K.
  float4 win[K];
#pragma unroll
  for (int i = 0; i < K - 1; ++i) {
    const int l = l0 - (K - 1) + i;
    if (l >= 0) {
      win[i] = xb[(size_t)l * C4];
    } else {
      win[i] = make_float4(0.f, 0.f, 0.f, 0.f);
    }
  }

#pragma unroll
  for (int i = 0; i < LT; ++i) {
    const int l = l0 + i;
    win[(i + K - 1) % K] = xb[(size_t)l * C4];
    float4 acc = bv;
#pragma unroll
    for (int k = 0; k < K; ++k) {
      const float4 v = win[(i + k) % K];
      acc.x = fmaf(wk[k][0], v.x, acc.x);
      acc.y = fmaf(wk[k][1], v.y, acc.y);
      acc.z = fmaf(wk[k][2], v.z, acc.z);
      acc.w = fmaf(wk[k][3], v.w, acc.w);
    }
    yb[(size_t)l * C4] = acc;
  }
}

extern "C" void kernel_launch(void* const* d_in, const int* in_sizes, int n_in,
                              void* d_out, int out_size, void* d_ws, size_t ws_size,
                              hipStream_t stream) {
  const float4* x    = (const float4*)d_in[0];   // [B, L, C] f32, viewed as float4
  const float*  w    = (const float*)d_in[1];    // [C, 1, K]
  const float*  bias = (const float*)d_in[2];    // [C]
  float4*       y    = (float4*)d_out;           // [B, L, C] f32

  const int B = 8;
  dim3 grid(Lc / LT, B, 1);   // 256 x 8 = 2048 blocks
  dim3 block(C4, 1, 1);       // 256 threads, one float4-lane per 4 channels
  dwconv_kernel<<<grid, block, 0, stream>>>(x, w, bias, y);
}

// Round 4
// 47.429 us; speedup vs baseline: 1.1051x; 1.1051x over previous
//
#include <hip/hip_runtime.h>

// Causal depthwise Conv1d: x[B,L,C] f32, weight[C,1,K] f32, bias[C] f32.
// y[b,l,c] = bias[c] + sum_k w[c,k] * x[b, l-6+k, c], zero-pad left.
// B=8, L=4096, C=1024, K=7. HBM-bound streaming kernel.
//
// R4 (= R3 + compile fix): deep memory-level parallelism. Absolute-indexed
// register window v[38] (6 halo + 32 tile), loads in batches of 4 with 2
// batches prefetched ahead (~8 outstanding 16B loads/wave). Nontemporal
// stores for y via native vector type (never re-read). XCD-chunked tile
// remap so adjacent tiles (shared halo) hit the same per-XCD L2.

typedef float f32x4 __attribute__((ext_vector_type(4)));

constexpr int Lc = 4096;
constexpr int C4 = 256;   // C/4 float4 lanes
constexpr int K  = 7;
constexpr int LT = 32;    // L positions per block
constexpr int NB = LT / 4;

__global__ __launch_bounds__(256, 4) void dwconv_kernel(
    const f32x4* __restrict__ x, const float* __restrict__ w,
    const float* __restrict__ bias, f32x4* __restrict__ y) {
  const int c4 = threadIdx.x;                      // 0..255 -> channels c4*4..+3
  const int bx = blockIdx.x;                       // 0..127
  const int tile = ((bx & 7) << 4) | (bx >> 3);    // XCD-chunked bijective remap
  const int l0 = tile * LT;
  const int b  = blockIdx.y;
  const int c  = c4 * 4;

  // Weights: 28 contiguous floats at w + c*7 (16B-aligned since c*7*4 = 112*c4).
  float ww[28];  // ww[i*4+j] = w[c*7 + i*4 + j] = channel (c + (i*4+j)/7), tap (i*4+j)%7
  {
    const f32x4* wv = reinterpret_cast<const f32x4*>(w + (size_t)c * K);
#pragma unroll
    for (int i = 0; i < 7; ++i) {
      f32x4 t = wv[i];
      ww[i * 4 + 0] = t.x; ww[i * 4 + 1] = t.y;
      ww[i * 4 + 2] = t.z; ww[i * 4 + 3] = t.w;
    }
  }
  const f32x4 bv = reinterpret_cast<const f32x4*>(bias)[c4];

  const f32x4* xb = x + (size_t)b * Lc * C4 + c4;
  f32x4*       yb = y + (size_t)b * Lc * C4 + c4;

  // Register window: v[i] = x[l0 - 6 + i], i = 0..37. Absolute indexing,
  // fully unrolled -> compiler tracks liveness (max ~18 live at once).
  f32x4 v[LT + 6];
  const f32x4 fz = {0.f, 0.f, 0.f, 0.f};
#pragma unroll
  for (int i = 0; i < 6; ++i) {
    const int l = l0 - 6 + i;
    v[i] = (l >= 0) ? xb[(size_t)l * C4] : fz;
  }
  // Prologue: batches 0 and 1 (8 loads in flight).
#pragma unroll
  for (int i = 0; i < 8; ++i) {
    v[6 + i] = xb[(size_t)(l0 + i) * C4];
  }

#pragma unroll
  for (int jb = 0; jb < NB; ++jb) {
    // Prefetch batch jb+2 (keeps ~8 loads outstanding through the compute).
    if (jb + 2 < NB) {
#pragma unroll
      for (int i = 0; i < 4; ++i) {
        v[6 + (jb + 2) * 4 + i] = xb[(size_t)(l0 + (jb + 2) * 4 + i) * C4];
      }
    }
    // Compute + store batch jb.
#pragma unroll
    for (int i = 0; i < 4; ++i) {
      const int li = jb * 4 + i;
      f32x4 acc = bv;
#pragma unroll
      for (int k = 0; k < K; ++k) {
        const f32x4 xv = v[li + k];
        // ww layout: channel j's tap k is ww[j*7 + k]
        acc.x = fmaf(ww[0 * 7 + k], xv.x, acc.x);
        acc.y = fmaf(ww[1 * 7 + k], xv.y, acc.y);
        acc.z = fmaf(ww[2 * 7 + k], xv.z, acc.z);
        acc.w = fmaf(ww[3 * 7 + k], xv.w, acc.w);
      }
      __builtin_nontemporal_store(acc, &yb[(size_t)(l0 + li) * C4]);
    }
  }
}

extern "C" void kernel_launch(void* const* d_in, const int* in_sizes, int n_in,
                              void* d_out, int out_size, void* d_ws, size_t ws_size,
                              hipStream_t stream) {
  const f32x4* x    = (const f32x4*)d_in[0];
  const float* w    = (const float*)d_in[1];
  const float* bias = (const float*)d_in[2];
  f32x4*       y    = (f32x4*)d_out;

  const int B = 8;
  dim3 grid(Lc / LT, B, 1);   // 128 x 8 = 1024 blocks
  dim3 block(C4, 1, 1);
  dwconv_kernel<<<grid, block, 0, stream>>>(x, w, bias, y);
}

// Round 5
// 45.963 us; speedup vs baseline: 1.1404x; 1.0319x over previous
//
#include <hip/hip_runtime.h>

// Causal depthwise Conv1d: x[B,L,C] f32, weight[C,1,K] f32, bias[C] f32.
// y[b,l,c] = bias[c] + sum_k w[c,k] * x[b, l-6+k, c], zero-pad left.
// B=8, L=4096, C=1024, K=7. Latency-bound streaming kernel.
//
// R5: R4 + sched_barrier(0) fences to FORCE the 2-batch-ahead load pipeline.
// R4 showed VGPR=36: the compiler sank all loads to just-before-use (1 load
// in flight). Fences between {prefetch batch jb+2} and {compute batch jb}
// make that sinking illegal -> 8 outstanding 16B loads/wave, waitcnt vmcnt(8).

typedef float f32x4 __attribute__((ext_vector_type(4)));

constexpr int Lc = 4096;
constexpr int C4 = 256;   // C/4 float4 lanes
constexpr int K  = 7;
constexpr int LT = 32;    // L positions per block
constexpr int NB = LT / 4;

__global__ __launch_bounds__(256, 4) void dwconv_kernel(
    const f32x4* __restrict__ x, const float* __restrict__ w,
    const float* __restrict__ bias, f32x4* __restrict__ y) {
  const int c4 = threadIdx.x;                      // 0..255 -> channels c4*4..+3
  const int bx = blockIdx.x;                       // 0..127
  const int tile = ((bx & 7) << 4) | (bx >> 3);    // XCD-chunked bijective remap
  const int l0 = tile * LT;
  const int b  = blockIdx.y;
  const int c  = c4 * 4;

  // Weights: 28 contiguous floats at w + c*7 (16B-aligned since c*7*4 = 112*c4).
  float ww[28];  // ww[j*7 + k] = channel (c+j), tap k
  {
    const f32x4* wv = reinterpret_cast<const f32x4*>(w + (size_t)c * K);
#pragma unroll
    for (int i = 0; i < 7; ++i) {
      f32x4 t = wv[i];
      ww[i * 4 + 0] = t.x; ww[i * 4 + 1] = t.y;
      ww[i * 4 + 2] = t.z; ww[i * 4 + 3] = t.w;
    }
  }
  const f32x4 bv = reinterpret_cast<const f32x4*>(bias)[c4];

  const f32x4* xb = x + (size_t)b * Lc * C4 + c4;
  f32x4*       yb = y + (size_t)b * Lc * C4 + c4;

  // Register window: v[i] = x[l0 - 6 + i], i = 0..37.
  f32x4 v[LT + 6];
  const f32x4 fz = {0.f, 0.f, 0.f, 0.f};
#pragma unroll
  for (int i = 0; i < 6; ++i) {
    const int l = l0 - 6 + i;
    v[i] = (l >= 0) ? xb[(size_t)l * C4] : fz;
  }
  // Prologue: batches 0 and 1 (8 loads in flight).
#pragma unroll
  for (int i = 0; i < 8; ++i) {
    v[6 + i] = xb[(size_t)(l0 + i) * C4];
  }
  __builtin_amdgcn_sched_barrier(0);  // loads above stay above

#pragma unroll
  for (int jb = 0; jb < NB; ++jb) {
    // Prefetch batch jb+2 (keeps 8 loads outstanding through the compute).
    if (jb + 2 < NB) {
#pragma unroll
      for (int i = 0; i < 4; ++i) {
        v[6 + (jb + 2) * 4 + i] = xb[(size_t)(l0 + (jb + 2) * 4 + i) * C4];
      }
    }
    __builtin_amdgcn_sched_barrier(0);  // prefetch may not sink below
    // Compute + store batch jb (needs only batch jb -> s_waitcnt vmcnt(8)).
#pragma unroll
    for (int i = 0; i < 4; ++i) {
      const int li = jb * 4 + i;
      f32x4 acc = bv;
#pragma unroll
      for (int k = 0; k < K; ++k) {
        const f32x4 xv = v[li + k];
        acc.x = fmaf(ww[0 * 7 + k], xv.x, acc.x);
        acc.y = fmaf(ww[1 * 7 + k], xv.y, acc.y);
        acc.z = fmaf(ww[2 * 7 + k], xv.z, acc.z);
        acc.w = fmaf(ww[3 * 7 + k], xv.w, acc.w);
      }
      __builtin_nontemporal_store(acc, &yb[(size_t)(l0 + li) * C4]);
    }
    __builtin_amdgcn_sched_barrier(0);  // compute may not float up past prefetch
  }
}

extern "C" void kernel_launch(void* const* d_in, const int* in_sizes, int n_in,
                              void* d_out, int out_size, void* d_ws, size_t ws_size,
                              hipStream_t stream) {
  const f32x4* x    = (const f32x4*)d_in[0];
  const float* w    = (const float*)d_in[1];
  const float* bias = (const float*)d_in[2];
  f32x4*       y    = (f32x4*)d_out;

  const int B = 8;
  dim3 grid(Lc / LT, B, 1);   // 128 x 8 = 1024 blocks
  dim3 block(C4, 1, 1);
  dwconv_kernel<<<grid, block, 0, stream>>>(x, w, bias, y);
}

// Round 6
// 44.864 us; speedup vs baseline: 1.1683x; 1.0245x over previous
//
#include <hip/hip_runtime.h>

// Causal depthwise Conv1d: x[B,L,C] f32, weight[C,1,K] f32, bias[C] f32.
// y[b,l,c] = bias[c] + sum_k w[c,k] * x[b, l-6+k, c], zero-pad left.
// B=8, L=4096, C=1024, K=7. Bound by delivered memory BW (~7 TB/s incl. L2/L3).
//
// R6: LT=64 (halves halo + weight re-read traffic, -8% issued bytes),
// PF=3-deep forced load pipeline (12 outstanding 16B loads/wave) with
// sched_barrier fences, launch_bounds(256,2) so the window can't spill.
// Nontemporal y stores; XCD-chunked tile remap for halo L2 sharing.

typedef float f32x4 __attribute__((ext_vector_type(4)));

constexpr int Lc = 4096;
constexpr int C4 = 256;   // C/4 float4 lanes
constexpr int K  = 7;
constexpr int LT = 64;    // L positions per block
constexpr int NB = LT / 4;
constexpr int PF = 3;     // prefetch distance in batches

__global__ __launch_bounds__(256, 2) void dwconv_kernel(
    const f32x4* __restrict__ x, const float* __restrict__ w,
    const float* __restrict__ bias, f32x4* __restrict__ y) {
  const int c4 = threadIdx.x;                      // 0..255 -> channels c4*4..+3
  const int bx = blockIdx.x;                       // 0..63
  const int tile = ((bx & 7) << 3) | (bx >> 3);    // XCD-chunked bijective remap (8x8)
  const int l0 = tile * LT;
  const int b  = blockIdx.y;
  const int c  = c4 * 4;

  // Weights: 28 contiguous floats at w + c*7 (16B-aligned since c*7*4 = 112*c4).
  float ww[28];  // ww[j*7 + k] = channel (c+j), tap k
  {
    const f32x4* wv = reinterpret_cast<const f32x4*>(w + (size_t)c * K);
#pragma unroll
    for (int i = 0; i < 7; ++i) {
      f32x4 t = wv[i];
      ww[i * 4 + 0] = t.x; ww[i * 4 + 1] = t.y;
      ww[i * 4 + 2] = t.z; ww[i * 4 + 3] = t.w;
    }
  }
  const f32x4 bv = reinterpret_cast<const f32x4*>(bias)[c4];

  const f32x4* xb = x + (size_t)b * Lc * C4 + c4;
  f32x4*       yb = y + (size_t)b * Lc * C4 + c4;

  // Register window: v[i] = x[l0 - 6 + i], i = 0..LT+5. Absolute indexing,
  // fully unrolled; fences keep the PF-deep pipeline alive.
  f32x4 v[LT + 6];
  const f32x4 fz = {0.f, 0.f, 0.f, 0.f};
#pragma unroll
  for (int i = 0; i < 6; ++i) {
    const int l = l0 - 6 + i;
    v[i] = (l >= 0) ? xb[(size_t)l * C4] : fz;
  }
  // Prologue: batches 0..PF-1 (12 loads in flight).
#pragma unroll
  for (int i = 0; i < PF * 4; ++i) {
    v[6 + i] = xb[(size_t)(l0 + i) * C4];
  }
  __builtin_amdgcn_sched_barrier(0);  // prologue loads stay above

#pragma unroll
  for (int jb = 0; jb < NB; ++jb) {
    // Prefetch batch jb+PF (keeps 12 loads outstanding through the compute).
    if (jb + PF < NB) {
#pragma unroll
      for (int i = 0; i < 4; ++i) {
        v[6 + (jb + PF) * 4 + i] = xb[(size_t)(l0 + (jb + PF) * 4 + i) * C4];
      }
    }
    __builtin_amdgcn_sched_barrier(0);  // prefetch may not sink below
    // Compute + store batch jb (waits only for its own batch).
#pragma unroll
    for (int i = 0; i < 4; ++i) {
      const int li = jb * 4 + i;
      f32x4 acc = bv;
#pragma unroll
      for (int k = 0; k < K; ++k) {
        const f32x4 xv = v[li + k];
        acc.x = fmaf(ww[0 * 7 + k], xv.x, acc.x);
        acc.y = fmaf(ww[1 * 7 + k], xv.y, acc.y);
        acc.z = fmaf(ww[2 * 7 + k], xv.z, acc.z);
        acc.w = fmaf(ww[3 * 7 + k], xv.w, acc.w);
      }
      __builtin_nontemporal_store(acc, &yb[(size_t)(l0 + li) * C4]);
    }
    __builtin_amdgcn_sched_barrier(0);  // compute may not float up past prefetch
  }
}

extern "C" void kernel_launch(void* const* d_in, const int* in_sizes, int n_in,
                              void* d_out, int out_size, void* d_ws, size_t ws_size,
                              hipStream_t stream) {
  const f32x4* x    = (const f32x4*)d_in[0];
  const float* w    = (const float*)d_in[1];
  const float* bias = (const float*)d_in[2];
  f32x4*       y    = (f32x4*)d_out;

  const int B = 8;
  dim3 grid(Lc / LT, B, 1);   // 64 x 8 = 512 blocks (2 per CU)
  dim3 block(C4, 1, 1);
  dwconv_kernel<<<grid, block, 0, stream>>>(x, w, bias, y);
}